// Round 3
// baseline (1311.906 us; speedup 1.0000x reference)
//
#include <hip/hip_runtime.h>

#define B_   32
#define HW_  196
#define C_   512
#define M_   (B_*HW_)    // 6272
#define HID_ 128
#define NBLK 18

__device__ __forceinline__ float gelu_f(float x) {
    // jax.nn.gelu default: tanh approximation
    float t = tanhf(0.7978845608028654f * (x + 0.044715f * x * x * x));
    return 0.5f * x * (1.0f + t);
}

// ---------- GEMM: out = gelu(A[M,K] @ W_blk[K,N] + bias_blk), fp32 ----------
#define BM 64
#define BN 64
#define BK 32
__global__ __launch_bounds__(256) void gemm_bias_gelu(
    const float* __restrict__ A, const float* __restrict__ Wall,
    const float* __restrict__ ball, int blk, float* __restrict__ out)
{
    __shared__ float As[BK][BM + 4];
    __shared__ float Bs[BK][BN];
    const int tid = threadIdx.x;
    const int tx = tid & 15, ty = tid >> 4;
    const int row0 = blockIdx.x * BM, col0 = blockIdx.y * BN;
    const float* W = Wall + (size_t)blk * C_ * C_;
    const float* bias = ball + (size_t)blk * C_;

    float acc[4][4];
    #pragma unroll
    for (int i = 0; i < 4; ++i)
        #pragma unroll
        for (int j = 0; j < 4; ++j) acc[i][j] = 0.f;

    for (int kt = 0; kt < C_; kt += BK) {
        #pragma unroll
        for (int l = 0; l < 2; ++l) {
            int f = tid + l * 256;
            int r = f >> 3, c4 = (f & 7) << 2;
            float4 v = *(const float4*)(A + (size_t)(row0 + r) * C_ + kt + c4);
            As[c4 + 0][r] = v.x; As[c4 + 1][r] = v.y;
            As[c4 + 2][r] = v.z; As[c4 + 3][r] = v.w;
        }
        #pragma unroll
        for (int l = 0; l < 2; ++l) {
            int f = tid + l * 256;
            int r = f >> 4, c4 = (f & 15) << 2;
            *(float4*)&Bs[r][c4] = *(const float4*)(W + (size_t)(kt + r) * C_ + col0 + c4);
        }
        __syncthreads();
        #pragma unroll
        for (int k = 0; k < BK; ++k) {
            float4 a4 = *(const float4*)&As[k][ty << 2];
            float4 b4 = *(const float4*)&Bs[k][tx << 2];
            float av[4] = {a4.x, a4.y, a4.z, a4.w};
            float bv[4] = {b4.x, b4.y, b4.z, b4.w};
            #pragma unroll
            for (int i = 0; i < 4; ++i)
                #pragma unroll
                for (int j = 0; j < 4; ++j) acc[i][j] += av[i] * bv[j];
        }
        __syncthreads();
    }

    float bb[4];
    #pragma unroll
    for (int j = 0; j < 4; ++j) bb[j] = bias[col0 + (tx << 2) + j];
    #pragma unroll
    for (int i = 0; i < 4; ++i) {
        int row = row0 + (ty << 2) + i;
        float4 o;
        o.x = gelu_f(acc[i][0] + bb[0]);
        o.y = gelu_f(acc[i][1] + bb[1]);
        o.z = gelu_f(acc[i][2] + bb[2]);
        o.w = gelu_f(acc[i][3] + bb[3]);
        *(float4*)(out + (size_t)row * C_ + col0 + (tx << 2)) = o;
    }
}

// ---------- global mean pool over 196 spatial positions ----------
__global__ __launch_bounds__(256) void pool_kernel(const float* __restrict__ nx,
                                                   float* __restrict__ pooled) {
    int b = blockIdx.x;
    int c = blockIdx.y * 256 + threadIdx.x;
    const float* p = nx + (size_t)b * HW_ * C_ + c;
    float s = 0.f;
    #pragma unroll 4
    for (int i = 0; i < HW_; ++i) s += p[(size_t)i * C_];
    pooled[b * C_ + c] = s * (1.f / 196.f);
}

// ---------- gating MLP + softmax over the 3 anchors; one block per batch ----------
__global__ __launch_bounds__(256) void gate_kernel(const float* __restrict__ pooled,
    const float* __restrict__ fc1w, const float* __restrict__ fc1b,
    const float* __restrict__ fc2w, const float* __restrict__ fc2b,
    int t, float* __restrict__ gates)
{
    __shared__ float sp[C_];
    __shared__ float sh[HID_];
    const int b = blockIdx.x, tid = threadIdx.x;
    sp[tid]       = pooled[b * C_ + tid];
    sp[tid + 256] = pooled[b * C_ + tid + 256];
    __syncthreads();
    if (tid < HID_) {
        const float* w = fc1w + (size_t)t * C_ * HID_ + tid;
        float s = fc1b[t * HID_ + tid];
        for (int c = 0; c < C_; ++c) s += sp[c] * w[(size_t)c * HID_];
        sh[tid] = gelu_f(s);
    }
    __syncthreads();
    #pragma unroll
    for (int cc = 0; cc < 2; ++cc) {
        int c = tid + cc * 256;
        const float* w2 = fc2w + (size_t)t * HID_ * (3 * C_) + c;
        float l0 = fc2b[t * 3 * C_ + c];
        float l1 = fc2b[t * 3 * C_ + C_ + c];
        float l2 = fc2b[t * 3 * C_ + 2 * C_ + c];
        for (int j = 0; j < HID_; ++j) {
            float h = sh[j];
            const float* r = w2 + (size_t)j * 3 * C_;
            l0 += h * r[0];
            l1 += h * r[C_];
            l2 += h * r[2 * C_];
        }
        float m  = fmaxf(l0, fmaxf(l1, l2));
        float e0 = expf(l0 - m), e1 = expf(l1 - m), e2 = expf(l2 - m);
        float inv = 1.f / (e0 + e1 + e2);
        gates[(size_t)b * 3 * C_ + c]          = e0 * inv;
        gates[(size_t)b * 3 * C_ + C_ + c]     = e1 * inv;
        gates[(size_t)b * 3 * C_ + 2 * C_ + c] = e2 * inv;
    }
}

// ---------- nx += gamma * sum_a gates[b,a,c]*anchor_a ; optional final fp32 out ----------
__global__ __launch_bounds__(256) void routed_add_kernel(float* __restrict__ nx,
    const float* __restrict__ a0, const float* __restrict__ a1, const float* __restrict__ a2,
    const float* __restrict__ gates, const float* __restrict__ gammas, int t,
    float* __restrict__ outf)
{
    int idx = blockIdx.x * 256 + threadIdx.x;   // grid sized exactly NB/256
    int c = idx & (C_ - 1);
    int b = idx / (HW_ * C_);
    const float* g = gates + (size_t)b * 3 * C_;
    float gamma = gammas[t];
    float v = nx[idx] + gamma * (g[c] * a0[idx] + g[C_ + c] * a1[idx] + g[2 * C_ + c] * a2[idx]);
    if (outf) outf[idx] = v;
    else      nx[idx] = v;
}

extern "C" void kernel_launch(void* const* d_in, const int* in_sizes, int n_in,
                              void* d_out, int out_size, void* d_ws, size_t ws_size,
                              hipStream_t stream)
{
    const float* x      = (const float*)d_in[0];
    const float* blockw = (const float*)d_in[1];
    const float* blockb = (const float*)d_in[2];
    const float* fc1w   = (const float*)d_in[3];
    const float* fc1b   = (const float*)d_in[4];
    const float* fc2w   = (const float*)d_in[5];
    const float* fc2b   = (const float*)d_in[6];
    const float* gammas = (const float*)d_in[7];
    float* out = (float*)d_out;

    const size_t NB = (size_t)M_ * C_;   // 3,211,264 floats per activation buffer
    float* P0 = (float*)d_ws;
    float* P1 = P0 + NB;
    float* A0 = P0 + 2 * NB;
    float* A1 = P0 + 3 * NB;
    float* A2 = P0 + 4 * NB;
    float* pooled = P0 + 5 * NB;           // 32*512
    float* gates  = pooled + B_ * C_;      // 32*3*512

    // x (fp32 input) feeds block 0 directly; anchors (blocks 1,4,9) pinned A0/A1/A2
    const float* ins[NBLK]  = {x,  P0, A0, P0, P1, A1, P0, P1, P0, P1, A2, P0, P1, P0, P1, P0, P1, P0};
    float*       outs[NBLK] = {P0, A0, P0, P1, A1, P0, P1, P0, P1, A2, P0, P1, P0, P1, P0, P1, P0, P1};

    for (int i = 0; i < NBLK; ++i) {
        gemm_bias_gelu<<<dim3(M_ / BM, C_ / BN), 256, 0, stream>>>(
            ins[i], blockw, blockb, i, outs[i]);
        int t = (i == 11) ? 0 : (i == 14) ? 1 : (i == 17) ? 2 : -1;
        if (t >= 0) {
            pool_kernel<<<dim3(B_, 2), 256, 0, stream>>>(outs[i], pooled);
            gate_kernel<<<B_, 256, 0, stream>>>(pooled, fc1w, fc1b, fc2w, fc2b, t, gates);
            routed_add_kernel<<<(int)(NB / 256), 256, 0, stream>>>(
                outs[i], A0, A1, A2, gates, gammas, t,
                (t == 2) ? out : (float*)nullptr);
        }
    }
}

// Round 4
// 550.692 us; speedup vs baseline: 2.3823x; 2.3823x over previous
//
#include <hip/hip_runtime.h>

#define B_   32
#define HW_  196
#define C_   512
#define M_   (B_*HW_)    // 6272
#define HID_ 128
#define NBLK 18

typedef _Float16 f16;
typedef _Float16 f16x8 __attribute__((ext_vector_type(8)));
typedef float    f32x4 __attribute__((ext_vector_type(4)));

__device__ __forceinline__ float gelu_f(float x) {
    float t = tanhf(0.7978845608028654f * (x + 0.044715f * x * x * x));
    return 0.5f * x * (1.0f + t);
}

// ---------- weights: fp32 [blk][k][n] -> fp16 transposed [blk][n][k] ----------
__global__ __launch_bounds__(256) void conv_w(const float* __restrict__ W,
                                              f16* __restrict__ Wt) {
    __shared__ f16 sh[64][72];
    const int blk = blockIdx.z, k0 = blockIdx.x * 64, n0 = blockIdx.y * 64;
    const int tid = threadIdx.x;
    const float* Wb = W + (size_t)blk * C_ * C_;
    #pragma unroll
    for (int i = 0; i < 4; ++i) {
        int s = tid + i * 256, r = s >> 4, c4 = (s & 15) << 2;
        float4 v = *(const float4*)&Wb[(size_t)(k0 + r) * C_ + n0 + c4];
        sh[r][c4 + 0] = (f16)v.x; sh[r][c4 + 1] = (f16)v.y;
        sh[r][c4 + 2] = (f16)v.z; sh[r][c4 + 3] = (f16)v.w;
    }
    __syncthreads();
    #pragma unroll
    for (int i = 0; i < 2; ++i) {
        int s = tid + i * 256, r = s >> 3, c8 = (s & 7) << 3;
        f16x8 o;
        #pragma unroll
        for (int j = 0; j < 8; ++j) o[j] = sh[c8 + j][r];
        *(f16x8*)&Wt[(size_t)blk * C_ * C_ + (size_t)(n0 + r) * C_ + k0 + c8] = o;
    }
}

// ---------- x: fp32 -> fp16 ----------
__global__ __launch_bounds__(256) void conv_x(const float* __restrict__ in,
                                              f16* __restrict__ out) {
    int i = blockIdx.x * 256 + threadIdx.x;
    out[i] = (f16)in[i];
}

// ---------- MFMA GEMM: out = gelu(A[M,K]@W_blk[K,N] + b), fp16 in/out, fp32 acc ----------
#define BM 64
#define BN 128
#define BK 64
#define LDK 72   // BK + 8 halfs pad: row stride 144B (16B-aligned, conflict-optimal)
__global__ __launch_bounds__(128) void gemm_f16(
    const f16* __restrict__ A, const f16* __restrict__ Wt,
    const float* __restrict__ ball, int blk, f16* __restrict__ out)
{
    __shared__ f16 As[BM][LDK];
    __shared__ f16 Ws[BN][LDK];
    const int tid = threadIdx.x;
    const int wave = tid >> 6, lane = tid & 63;
    const int m15 = lane & 15, q = lane >> 4;
    const int row0 = blockIdx.x * BM, col0 = blockIdx.y * BN;
    const f16* Wb = Wt + (size_t)blk * C_ * C_;
    const float* bias = ball + (size_t)blk * C_;

    f32x4 acc[4][4];
    #pragma unroll
    for (int i = 0; i < 4; ++i)
        #pragma unroll
        for (int j = 0; j < 4; ++j) acc[i][j] = (f32x4)0.f;

    for (int kt = 0; kt < C_; kt += BK) {
        // stage A: 64 rows x 64 k (8KB): 128 thr x 4 x 16B
        #pragma unroll
        for (int i = 0; i < 4; ++i) {
            int s = tid + i * 128, r = s >> 3, c8 = (s & 7) << 3;
            *(f16x8*)&As[r][c8] = *(const f16x8*)&A[(size_t)(row0 + r) * C_ + kt + c8];
        }
        // stage Wt: 128 rows x 64 k (16KB): 128 thr x 8 x 16B
        #pragma unroll
        for (int i = 0; i < 8; ++i) {
            int s = tid + i * 128, r = s >> 3, c8 = (s & 7) << 3;
            *(f16x8*)&Ws[r][c8] = *(const f16x8*)&Wb[(size_t)(col0 + r) * C_ + kt + c8];
        }
        __syncthreads();
        #pragma unroll
        for (int kk = 0; kk < BK; kk += 32) {
            f16x8 af[4], bf[4];
            #pragma unroll
            for (int i = 0; i < 4; ++i)
                af[i] = *(const f16x8*)&As[i * 16 + m15][kk + q * 8];
            #pragma unroll
            for (int j = 0; j < 4; ++j)
                bf[j] = *(const f16x8*)&Ws[wave * 64 + j * 16 + m15][kk + q * 8];
            #pragma unroll
            for (int i = 0; i < 4; ++i)
                #pragma unroll
                for (int j = 0; j < 4; ++j)
                    acc[i][j] = __builtin_amdgcn_mfma_f32_16x16x32_f16(af[i], bf[j], acc[i][j], 0, 0, 0);
        }
        __syncthreads();
    }

    // epilogue: C/D layout col=lane&15, row=quad*4+reg (HW-verified, dtype-indep)
    float bcol[4];
    #pragma unroll
    for (int j = 0; j < 4; ++j) bcol[j] = bias[col0 + wave * 64 + j * 16 + m15];
    #pragma unroll
    for (int i = 0; i < 4; ++i) {
        #pragma unroll
        for (int r = 0; r < 4; ++r) {
            int row = row0 + i * 16 + q * 4 + r;
            #pragma unroll
            for (int j = 0; j < 4; ++j) {
                int col = col0 + wave * 64 + j * 16 + m15;
                out[(size_t)row * C_ + col] = (f16)gelu_f(acc[i][j][r] + bcol[j]);
            }
        }
    }
}

// ---------- global mean pool (fp16 in, fp32 out) ----------
__global__ __launch_bounds__(256) void pool_kernel(const f16* __restrict__ nx,
                                                   float* __restrict__ pooled) {
    int b = blockIdx.x;
    int c = blockIdx.y * 256 + threadIdx.x;
    const f16* p = nx + (size_t)b * HW_ * C_ + c;
    float s = 0.f;
    #pragma unroll 4
    for (int i = 0; i < HW_; ++i) s += (float)p[(size_t)i * C_];
    pooled[b * C_ + c] = s * (1.f / 196.f);
}

// ---------- gating MLP + softmax over anchors (fp32 weights from d_in) ----------
__global__ __launch_bounds__(256) void gate_kernel(const float* __restrict__ pooled,
    const float* __restrict__ fc1w, const float* __restrict__ fc1b,
    const float* __restrict__ fc2w, const float* __restrict__ fc2b,
    int t, float* __restrict__ gates)
{
    __shared__ float sp[C_];
    __shared__ float sh[HID_];
    const int b = blockIdx.x, tid = threadIdx.x;
    sp[tid]       = pooled[b * C_ + tid];
    sp[tid + 256] = pooled[b * C_ + tid + 256];
    __syncthreads();
    if (tid < HID_) {
        const float* w = fc1w + (size_t)t * C_ * HID_ + tid;
        float s = fc1b[t * HID_ + tid];
        for (int c = 0; c < C_; ++c) s += sp[c] * w[(size_t)c * HID_];
        sh[tid] = gelu_f(s);
    }
    __syncthreads();
    #pragma unroll
    for (int cc = 0; cc < 2; ++cc) {
        int c = tid + cc * 256;
        const float* w2 = fc2w + (size_t)t * HID_ * (3 * C_) + c;
        float l0 = fc2b[t * 3 * C_ + c];
        float l1 = fc2b[t * 3 * C_ + C_ + c];
        float l2 = fc2b[t * 3 * C_ + 2 * C_ + c];
        for (int j = 0; j < HID_; ++j) {
            float h = sh[j];
            const float* r = w2 + (size_t)j * 3 * C_;
            l0 += h * r[0];
            l1 += h * r[C_];
            l2 += h * r[2 * C_];
        }
        float m  = fmaxf(l0, fmaxf(l1, l2));
        float e0 = expf(l0 - m), e1 = expf(l1 - m), e2 = expf(l2 - m);
        float inv = 1.f / (e0 + e1 + e2);
        gates[(size_t)b * 3 * C_ + c]          = e0 * inv;
        gates[(size_t)b * 3 * C_ + C_ + c]     = e1 * inv;
        gates[(size_t)b * 3 * C_ + 2 * C_ + c] = e2 * inv;
    }
}

// ---------- nx += gamma * sum_a gates[b,a,c]*anchor_a ; t==2 also writes fp32 out ----------
__global__ __launch_bounds__(256) void routed_add_kernel(f16* __restrict__ nx,
    const f16* __restrict__ a0, const f16* __restrict__ a1, const f16* __restrict__ a2,
    const float* __restrict__ gates, const float* __restrict__ gammas, int t,
    float* __restrict__ outf)
{
    int idx = blockIdx.x * 256 + threadIdx.x;
    int c = idx & (C_ - 1);
    int b = idx / (HW_ * C_);
    const float* g = gates + (size_t)b * 3 * C_;
    float gamma = gammas[t];
    float v = (float)nx[idx] + gamma * (g[c] * (float)a0[idx] + g[C_ + c] * (float)a1[idx]
                                        + g[2 * C_ + c] * (float)a2[idx]);
    if (outf) outf[idx] = v;      // final target: fp32 to d_out
    else      nx[idx] = (f16)v;   // intermediate: fp16 in-place
}

extern "C" void kernel_launch(void* const* d_in, const int* in_sizes, int n_in,
                              void* d_out, int out_size, void* d_ws, size_t ws_size,
                              hipStream_t stream)
{
    const float* x      = (const float*)d_in[0];
    const float* blockw = (const float*)d_in[1];
    const float* blockb = (const float*)d_in[2];
    const float* fc1w   = (const float*)d_in[3];
    const float* fc1b   = (const float*)d_in[4];
    const float* fc2w   = (const float*)d_in[5];
    const float* fc2b   = (const float*)d_in[6];
    const float* gammas = (const float*)d_in[7];
    float* out = (float*)d_out;

    const size_t NB = (size_t)M_ * C_;            // 3,211,264 elems/activation
    f16* Wt = (f16*)d_ws;                          // 18*512*512 halfs = 9.44MB
    f16* P0 = Wt + (size_t)NBLK * C_ * C_;
    f16* P1 = P0 + NB;
    f16* A0 = P0 + 2 * NB;
    f16* A1 = P0 + 3 * NB;
    f16* A2 = P0 + 4 * NB;
    float* pooled = (float*)(P0 + 5 * NB);
    float* gates  = pooled + B_ * C_;

    conv_w<<<dim3(8, 8, NBLK), 256, 0, stream>>>(blockw, Wt);
    conv_x<<<(int)(NB / 256), 256, 0, stream>>>(x, P1);

    // x(fp16)=P1 feeds block 0; anchors (blocks 1,4,9 outputs) pinned A0/A1/A2
    const f16* ins[NBLK]  = {P1, P0, A0, P0, P1, A1, P0, P1, P0, P1, A2, P0, P1, P0, P1, P0, P1, P0};
    f16*       outs[NBLK] = {P0, A0, P0, P1, A1, P0, P1, P0, P1, A2, P0, P1, P0, P1, P0, P1, P0, P1};

    for (int i = 0; i < NBLK; ++i) {
        gemm_f16<<<dim3(M_ / BM, C_ / BN), 128, 0, stream>>>(
            ins[i], Wt, blockb, i, outs[i]);
        int t = (i == 11) ? 0 : (i == 14) ? 1 : (i == 17) ? 2 : -1;
        if (t >= 0) {
            pool_kernel<<<dim3(B_, 2), 256, 0, stream>>>(outs[i], pooled);
            gate_kernel<<<B_, 256, 0, stream>>>(pooled, fc1w, fc1b, fc2w, fc2b, t, gates);
            routed_add_kernel<<<(int)(NB / 256), 256, 0, stream>>>(
                outs[i], A0, A1, A2, gates, gammas, t,
                (t == 2) ? out : (float*)nullptr);
        }
    }
}